// Round 8
// baseline (197.873 us; speedup 1.0000x reference)
//
#include <hip/hip_runtime.h>

// PointVoxelizer: bucketed sorted-unique over bounded key domain.
// combined = batch*GXYZ + x*YZ + y*GZ + z in [0, 3.2e8).
// Points partitioned by key>>18 into 1221 buckets (2^18 cells = 32KB LDS
// bitmap); all random access in LDS. No global atomics.
// R6 profile-driven fixes:
//  - out_map scatter (2M random 4B stores -> 128MB partial-line writeback)
//    replaced by contiguous mapval[p] write + gather pass k7 (LLC-resident).
//  - pk pairs u64 -> u32 keys (pos[i] carries the back-mapping, coalesced).
//  - k6 LDS bitmap stored rank-swizzled sigma(w)=((w&7)<<10)|(w>>3) so the
//    8-words-per-thread prefix/enumerate reads are stride-1 (was 16-way
//    bank conflict, 4.8M conflict-cycles = ~15% of k6).
//
// Dispatches:
//   k1_keys_hist  : keys -> upt; per-(chunk,bucket) LDS histogram -> hist[c][b]
//   k2a_chunk_pre : per-bucket exclusive prefix over chunks -> tot
//   k2b_scan_tot  : 1-block scan of tot -> boff[NB+1]
//   k3_scatter    : keys into bucket regions (LDS cursors); pos[i] = slot
//   k4_count      : per-bucket LDS bitmap -> dcnt[b]
//   k6_emit       : per-bucket bitmap + swizzled word-prefix; enumerate ->
//                   coords/feats rows; per-pair rank -> mapval (contiguous);
//                   pad blocks fill tail rows + n_voxels
//   k7_map        : out_map[i] = valid ? mapval[pos[i]] : -1

namespace {

constexpr int GX = 1000, GY = 1000, GZ = 80;
constexpr int YZ = GY * GZ;                 // 80,000
constexpr int GXYZ = GX * YZ;               // 80,000,000
constexpr int TOTAL_CELLS = GXYZ * 4;       // 320,000,000 (< 2^31)
constexpr int BBITS = 18;
constexpr int BCELLS = 1 << BBITS;          // 262,144 cells / bucket
constexpr int NB = (TOTAL_CELLS + BCELLS - 1) >> BBITS;  // 1221
constexpr int BWORDS = BCELLS / 32;         // 8192 u32 (32KB LDS bitmap)
constexpr int NCHUNK = 1024;
static_assert(NCHUNK % 64 == 0, "k2a wave scan");

// ws layout (bytes):
//   [0,    8e6)   upt    u32[N]
//   [8e6, 16e6)   pk     u32[N]   (bucket-grouped keys)
//   [16e6,24e6)   pos    u32[N]   (point i -> slot p)
//   [24e6,32e6)   mapval f32[N]   (slot p -> rank)
//   [32e6,37.1e6) hist   u32[NCHUNK][NB]
//   [38e6, ..)    tot, boff, dcnt
constexpr size_t OFF_PK   = 8000000;
constexpr size_t OFF_POS  = 16000000;
constexpr size_t OFF_MVAL = 24000000;
constexpr size_t OFF_HIST = 32000000;
constexpr size_t OFF_TOT  = 38000000;
constexpr size_t OFF_BOFF = 38100000;
constexpr size_t OFF_DCNT = 38200000;

__device__ __forceinline__ int sw(int w) {  // rank-word -> LDS slot swizzle
  return ((w & 7) << 10) | (w >> 3);
}

__global__ void k1_keys_hist(const float* __restrict__ pts, const int* __restrict__ bi,
                             unsigned* __restrict__ upt, unsigned* __restrict__ hist,
                             int n, int cpb) {
  __shared__ unsigned h[NB];
  const int c = blockIdx.x;
  for (int b = threadIdx.x; b < NB; b += blockDim.x) h[b] = 0;
  __syncthreads();
  const int lo = c * cpb, hi = min(n, lo + cpb);
  for (int i = lo + threadIdx.x; i < hi; i += blockDim.x) {
    // Bit-exact mirror of reference: fp32 add/div/floor (non-contractible).
    float px = pts[3 * i + 0], py = pts[3 * i + 1], pz = pts[3 * i + 2];
    int vx = (int)floorf((px + 50.0f) / 0.1f);
    int vy = (int)floorf((py + 50.0f) / 0.1f);
    int vz = (int)floorf((pz + 5.0f) / 0.1f);
    bool valid = (vx >= 0) & (vy >= 0) & (vz >= 0) & (vx < GX) & (vy < GY) & (vz < GZ);
    unsigned u = 0xFFFFFFFFu;
    if (valid) {
      u = (unsigned)(bi[i] * GXYZ + vx * YZ + vy * GZ + vz);
      atomicAdd(&h[u >> BBITS], 1u);
    }
    upt[i] = u;
  }
  __syncthreads();
  for (int b = threadIdx.x; b < NB; b += blockDim.x)
    hist[(size_t)c * NB + b] = h[b];  // contiguous flush, no global atomics
}

// One wave per bucket: exclusive prefix of hist[*][b] across chunks (in place),
// bucket total -> tot[b].
__global__ void k2a_chunk_pre(unsigned* __restrict__ hist, unsigned* __restrict__ tot) {
  const int wid = (blockIdx.x * blockDim.x + threadIdx.x) >> 6;
  const int lane = threadIdx.x & 63;
  if (wid >= NB) return;
  unsigned run = 0;
  for (int c0 = 0; c0 < NCHUNK; c0 += 64) {
    const size_t idx = (size_t)(c0 + lane) * NB + wid;
    unsigned v = hist[idx];
    unsigned inc = v;
    for (int o = 1; o < 64; o <<= 1) {
      unsigned t = __shfl_up(inc, o);
      if (lane >= o) inc += t;
    }
    hist[idx] = run + inc - v;
    run += __shfl(inc, 63);
  }
  if (lane == 63) tot[wid] = run;
}

__global__ void k2b_scan_tot(const unsigned* __restrict__ tot, unsigned* __restrict__ boff) {
  __shared__ unsigned s[1024];
  const int tid = threadIdx.x;
  unsigned v0 = (2 * tid     < NB) ? tot[2 * tid]     : 0u;
  unsigned v1 = (2 * tid + 1 < NB) ? tot[2 * tid + 1] : 0u;
  unsigned t = v0 + v1;
  s[tid] = t;
  __syncthreads();
  for (int o = 1; o < 1024; o <<= 1) {
    unsigned add = (tid >= o) ? s[tid - o] : 0u;
    __syncthreads();
    s[tid] += add;
    __syncthreads();
  }
  unsigned excl = s[tid] - t;
  if (2 * tid     < NB) boff[2 * tid]     = excl;
  if (2 * tid + 1 < NB) boff[2 * tid + 1] = excl + v0;
  if (tid == 1023) boff[NB] = s[1023];
}

// Scatter keys into bucket regions; record each point's slot (pos, coalesced).
__global__ void k3_scatter(const unsigned* __restrict__ upt, const unsigned* __restrict__ hist,
                           const unsigned* __restrict__ boff, unsigned* __restrict__ pk,
                           unsigned* __restrict__ pos, int n, int cpb) {
  __shared__ unsigned cur[NB];
  const int c = blockIdx.x;
  for (int b = threadIdx.x; b < NB; b += blockDim.x)
    cur[b] = boff[b] + hist[(size_t)c * NB + b];
  __syncthreads();
  const int lo = c * cpb, hi = min(n, lo + cpb);
  for (int i = lo + threadIdx.x; i < hi; i += blockDim.x) {
    unsigned u = upt[i];
    if (u == 0xFFFFFFFFu) continue;
    unsigned p = atomicAdd(&cur[u >> BBITS], 1u);
    pk[p] = u;
    pos[i] = p;
  }
}

__global__ void __launch_bounds__(1024) k4_count(const unsigned* __restrict__ pk,
                                                 const unsigned* __restrict__ boff,
                                                 unsigned* __restrict__ dcnt) {
  __shared__ unsigned bits[BWORDS];
  __shared__ unsigned red[1024];
  const int b = blockIdx.x, tid = threadIdx.x;
  for (int w = tid; w < BWORDS; w += 1024) bits[w] = 0;
  __syncthreads();
  const unsigned lo = boff[b], hi = boff[b + 1];
  const unsigned base = (unsigned)b << BBITS;
  for (unsigned p = lo + tid; p < hi; p += 1024) {
    unsigned local = pk[p] - base;
    atomicOr(&bits[local >> 5], 1u << (local & 31));
  }
  __syncthreads();
  unsigned cnt = 0;
  for (int w = tid; w < BWORDS; w += 1024) cnt += __popc(bits[w]);
  red[tid] = cnt;
  __syncthreads();
  for (int o = 512; o > 0; o >>= 1) {
    if (tid < o) red[tid] += red[tid + o];
    __syncthreads();
  }
  if (tid == 0) dcnt[b] = red[0];
}

__global__ void __launch_bounds__(1024) k6_emit(
    const unsigned* __restrict__ pk, const unsigned* __restrict__ boff,
    const unsigned* __restrict__ dcnt, float* __restrict__ out_coords,
    float* __restrict__ out_feats, float* __restrict__ mapval,
    float* __restrict__ out_nvox, int n) {
  __shared__ unsigned bits[BWORDS];  // 32KB, rank-swizzled via sw()
  __shared__ unsigned wpre[BWORDS];  // 32KB, rank-swizzled
  __shared__ unsigned s[1024];       //  4KB
  const int tid = threadIdx.x;
  const int bid = blockIdx.x;

  if (bid >= NB) {
    // pad role: n_voxels = sum(dcnt); rows [nv, n) get coords=-1, feats=0
    unsigned part = 0;
    for (int k = tid; k < NB; k += 1024) part += dcnt[k];
    s[tid] = part;
    __syncthreads();
    for (int o = 512; o > 0; o >>= 1) {
      if (tid < o) s[tid] += s[tid + o];
      __syncthreads();
    }
    const unsigned nv = s[0];
    if (bid == NB && tid == 0) *out_nvox = (float)nv;
    const int row = (bid - NB) * 1024 + tid;
    if (row < n && (unsigned)row >= nv) {
      float* c = out_coords + (size_t)row * 4;
      c[0] = -1.0f; c[1] = -1.0f; c[2] = -1.0f; c[3] = -1.0f;
      float* f = out_feats + (size_t)row * 3;
      f[0] = 0.0f; f[1] = 0.0f; f[2] = 0.0f;
    }
    return;
  }

  // drank = sum(dcnt[0..bid))  (dcnt is L2-resident, redundant reads ~free)
  unsigned part = 0;
  for (int k = tid; k < bid; k += 1024) part += dcnt[k];
  s[tid] = part;
  __syncthreads();
  for (int o = 512; o > 0; o >>= 1) {
    if (tid < o) s[tid] += s[tid + o];
    __syncthreads();
  }
  const unsigned drank = s[0];
  __syncthreads();

  // build bucket bitmap (swizzled slots)
  for (int w = tid; w < BWORDS; w += 1024) bits[w] = 0;
  __syncthreads();
  const unsigned lo = boff[bid], hi = boff[bid + 1];
  const unsigned base = (unsigned)bid << BBITS;
  for (unsigned p = lo + tid; p < hi; p += 1024) {
    unsigned local = pk[p] - base;
    atomicOr(&bits[sw(local >> 5)], 1u << (local & 31));
  }
  __syncthreads();

  // per-word exclusive popcount prefix; thread owns rank-words 8t..8t+7,
  // which live at slots {t, 1024+t, ...} -> stride-1, conflict-free.
  unsigned c8[8];
  unsigned t = 0;
  #pragma unroll
  for (int j = 0; j < 8; j++) {
    unsigned p = __popc(bits[j * 1024 + tid]);
    c8[j] = t;
    t += p;
  }
  s[tid] = t;
  __syncthreads();
  for (int o = 1; o < 1024; o <<= 1) {
    unsigned add = (tid >= o) ? s[tid - o] : 0u;
    __syncthreads();
    s[tid] += add;
    __syncthreads();
  }
  const unsigned excl = s[tid] - t;
  #pragma unroll
  for (int j = 0; j < 8; j++) wpre[j * 1024 + tid] = excl + c8[j];
  __syncthreads();

  // enumerate set bits in rank order -> rows [drank, drank+dcnt[bid])
  #pragma unroll
  for (int j = 0; j < 8; j++) {
    const int slot = j * 1024 + tid;
    unsigned m = bits[slot];
    unsigned r = drank + wpre[slot];
    const unsigned lbase = (unsigned)(tid * 8 + j) << 5;
    while (m) {
      int bit = __ffs(m) - 1;
      m &= m - 1;
      unsigned u = base + lbase + (unsigned)bit;
      int bat = (int)(u / (unsigned)GXYZ);
      int rem = (int)(u % (unsigned)GXYZ);
      int x = rem / YZ, ry = rem % YZ;
      int y = ry / GZ, z = ry % GZ;
      float* cc = out_coords + (size_t)r * 4;
      cc[0] = (float)bat; cc[1] = (float)z; cc[2] = (float)y; cc[3] = (float)x;
      float* ff = out_feats + (size_t)r * 3;
      ff[0] = -50.0f + ((float)x + 0.5f) * 0.1f;
      ff[1] = -50.0f + ((float)y + 0.5f) * 0.1f;
      ff[2] = -5.0f + ((float)z + 0.5f) * 0.1f;
      r++;
    }
  }

  // per-pair rank -> mapval[p]  (CONTIGUOUS write; gather happens in k7)
  for (unsigned p = lo + tid; p < hi; p += 1024) {
    unsigned local = pk[p] - base;
    int slot = sw((int)(local >> 5));
    unsigned r = drank + wpre[slot] + (unsigned)__popc(bits[slot] & ((1u << (local & 31)) - 1u));
    mapval[p] = (float)r;
  }
}

__global__ void k7_map(const unsigned* __restrict__ upt, const unsigned* __restrict__ pos,
                       const float* __restrict__ mapval, float* __restrict__ out_map, int n) {
  int i = blockIdx.x * blockDim.x + threadIdx.x;
  if (i >= n) return;
  unsigned u = upt[i];
  if (u == 0xFFFFFFFFu) {  // branch form: pos[i] is poison for invalid points,
    out_map[i] = -1.0f;    // keep the dependent gather provably unreachable
    return;
  }
  out_map[i] = mapval[pos[i]];  // mapval is LLC-resident
}

}  // namespace

extern "C" void kernel_launch(void* const* d_in, const int* in_sizes, int n_in,
                              void* d_out, int out_size, void* d_ws, size_t ws_size,
                              hipStream_t stream) {
  const int N = in_sizes[0] / 3;
  const float* pts = (const float*)d_in[0];
  const int* bi = (const int*)d_in[1];
  float* out = (float*)d_out;

  unsigned* upt = (unsigned*)d_ws;
  unsigned* pk   = (unsigned*)((char*)d_ws + OFF_PK);
  unsigned* pos  = (unsigned*)((char*)d_ws + OFF_POS);
  float*    mval = (float*)((char*)d_ws + OFF_MVAL);
  unsigned* hist = (unsigned*)((char*)d_ws + OFF_HIST);
  unsigned* tot  = (unsigned*)((char*)d_ws + OFF_TOT);
  unsigned* boff = (unsigned*)((char*)d_ws + OFF_BOFF);
  unsigned* dcnt = (unsigned*)((char*)d_ws + OFF_DCNT);

  float* out_coords = out;            // [N,4]
  float* out_feats  = out + 4LL * N;  // [N,3]
  float* out_map    = out + 7LL * N;  // [N]
  float* out_nvox   = out + 8LL * N;  // scalar

  const int cpb = (N + NCHUNK - 1) / NCHUNK;
  const int pad_blocks = (N + 1023) / 1024;

  k1_keys_hist<<<NCHUNK, 256, 0, stream>>>(pts, bi, upt, hist, N, cpb);
  k2a_chunk_pre<<<(NB * 64 + 255) / 256, 256, 0, stream>>>(hist, tot);
  k2b_scan_tot<<<1, 1024, 0, stream>>>(tot, boff);
  k3_scatter<<<NCHUNK, 256, 0, stream>>>(upt, hist, boff, pk, pos, N, cpb);
  k4_count<<<NB, 1024, 0, stream>>>(pk, boff, dcnt);
  k6_emit<<<NB + pad_blocks, 1024, 0, stream>>>(pk, boff, dcnt, out_coords,
                                                out_feats, mval, out_nvox, N);
  k7_map<<<(N + 1023) / 1024, 1024, 0, stream>>>(upt, pos, mval, out_map, N);
}

// Round 9
// 177.559 us; speedup vs baseline: 1.1144x; 1.1144x over previous
//
#include <hip/hip_runtime.h>

// PointVoxelizer: bucketed sorted-unique over bounded key domain.
// combined = batch*GXYZ + x*YZ + y*GZ + z in [0, 3.2e8).
// Points partitioned by key>>18 into 1221 buckets (2^18 cells = 32KB LDS
// bitmap); all random access in LDS. No global atomics.
// R8 restructure: single bitmap build (k4) emits compacted distinct keys (dk)
// + local ranks (mapval); emit pass (k6) is pure coalesced copy/decode;
// map pass adds bucket-base rank from a 4.9KB drank table.
//
// Dispatches:
//   k1_keys_hist  : keys -> upt; per-(chunk,bucket) LDS histogram -> hist[c][b]
//   k2a_chunk_pre : per-bucket exclusive prefix over chunks -> tot
//   k2b_scan_tot  : 1-block scan of tot -> boff[NB+1]
//   k3_scatter    : keys into bucket regions (LDS cursors); pos[i] = slot
//   k4_rank       : per-bucket LDS bitmap + swizzled word-prefix ->
//                   dcnt[b]; dk[boff[b]+j]=j-th distinct key (compact);
//                   mapval[p]=local rank (contiguous)
//   k6_emit       : per-bucket drank (L2 reduce over dcnt); decode dk ->
//                   coords/feats rows (coalesced); drank_tbl[b];
//                   pad blocks fill tail rows + n_voxels
//   k7_map        : out_map[i] = valid ? drank_tbl[u>>18]+mapval[pos[i]] : -1

namespace {

constexpr int GX = 1000, GY = 1000, GZ = 80;
constexpr int YZ = GY * GZ;                 // 80,000
constexpr int GXYZ = GX * YZ;               // 80,000,000
constexpr int TOTAL_CELLS = GXYZ * 4;       // 320,000,000 (< 2^31)
constexpr int BBITS = 18;
constexpr int BCELLS = 1 << BBITS;          // 262,144 cells / bucket
constexpr int NB = (TOTAL_CELLS + BCELLS - 1) >> BBITS;  // 1221
constexpr int BWORDS = BCELLS / 32;         // 8192 u32 (32KB LDS bitmap)
constexpr int NCHUNK = 512;
static_assert(NCHUNK % 64 == 0, "k2a wave scan");

// ws layout (bytes):
//   [0,    8e6)   upt    u32[N]
//   [8e6, 16e6)   pk     u32[N]   (bucket-grouped keys)
//   [16e6,24e6)   pos    u32[N]   (point i -> slot p)
//   [24e6,32e6)   mapval u32[N]   (slot p -> local rank)
//   [32e6,40e6)   dk     u32[N]   (compacted distinct keys per bucket)
//   [40e6,42.6e6) hist   u32[NCHUNK][NB]
//   [43e6,..)     tot, boff, dcnt, drank
constexpr size_t OFF_PK    = 8000000;
constexpr size_t OFF_POS   = 16000000;
constexpr size_t OFF_MVAL  = 24000000;
constexpr size_t OFF_DK    = 32000000;
constexpr size_t OFF_HIST  = 40000000;
constexpr size_t OFF_TOT   = 43000000;
constexpr size_t OFF_BOFF  = 43100000;
constexpr size_t OFF_DCNT  = 43200000;
constexpr size_t OFF_DRANK = 43300000;

__device__ __forceinline__ int sw(int w) {  // rank-word -> LDS slot swizzle
  return ((w & 7) << 10) | (w >> 3);
}

__global__ void k1_keys_hist(const float* __restrict__ pts, const int* __restrict__ bi,
                             unsigned* __restrict__ upt, unsigned* __restrict__ hist,
                             int n, int cpb) {
  __shared__ unsigned h[NB];
  const int c = blockIdx.x;
  for (int b = threadIdx.x; b < NB; b += blockDim.x) h[b] = 0;
  __syncthreads();
  const int lo = c * cpb, hi = min(n, lo + cpb);
  for (int i = lo + threadIdx.x; i < hi; i += blockDim.x) {
    // Bit-exact mirror of reference: fp32 add/div/floor (non-contractible).
    float px = pts[3 * i + 0], py = pts[3 * i + 1], pz = pts[3 * i + 2];
    int vx = (int)floorf((px + 50.0f) / 0.1f);
    int vy = (int)floorf((py + 50.0f) / 0.1f);
    int vz = (int)floorf((pz + 5.0f) / 0.1f);
    bool valid = (vx >= 0) & (vy >= 0) & (vz >= 0) & (vx < GX) & (vy < GY) & (vz < GZ);
    unsigned u = 0xFFFFFFFFu;
    if (valid) {
      u = (unsigned)(bi[i] * GXYZ + vx * YZ + vy * GZ + vz);
      atomicAdd(&h[u >> BBITS], 1u);
    }
    upt[i] = u;
  }
  __syncthreads();
  for (int b = threadIdx.x; b < NB; b += blockDim.x)
    hist[(size_t)c * NB + b] = h[b];  // contiguous flush, no global atomics
}

// One wave per bucket: exclusive prefix of hist[*][b] across chunks (in place),
// bucket total -> tot[b].
__global__ void k2a_chunk_pre(unsigned* __restrict__ hist, unsigned* __restrict__ tot) {
  const int wid = (blockIdx.x * blockDim.x + threadIdx.x) >> 6;
  const int lane = threadIdx.x & 63;
  if (wid >= NB) return;
  unsigned run = 0;
  for (int c0 = 0; c0 < NCHUNK; c0 += 64) {
    const size_t idx = (size_t)(c0 + lane) * NB + wid;
    unsigned v = hist[idx];
    unsigned inc = v;
    for (int o = 1; o < 64; o <<= 1) {
      unsigned t = __shfl_up(inc, o);
      if (lane >= o) inc += t;
    }
    hist[idx] = run + inc - v;
    run += __shfl(inc, 63);
  }
  if (lane == 63) tot[wid] = run;
}

__global__ void k2b_scan_tot(const unsigned* __restrict__ tot, unsigned* __restrict__ boff) {
  __shared__ unsigned s[1024];
  const int tid = threadIdx.x;
  unsigned v0 = (2 * tid     < NB) ? tot[2 * tid]     : 0u;
  unsigned v1 = (2 * tid + 1 < NB) ? tot[2 * tid + 1] : 0u;
  unsigned t = v0 + v1;
  s[tid] = t;
  __syncthreads();
  for (int o = 1; o < 1024; o <<= 1) {
    unsigned add = (tid >= o) ? s[tid - o] : 0u;
    __syncthreads();
    s[tid] += add;
    __syncthreads();
  }
  unsigned excl = s[tid] - t;
  if (2 * tid     < NB) boff[2 * tid]     = excl;
  if (2 * tid + 1 < NB) boff[2 * tid + 1] = excl + v0;
  if (tid == 1023) boff[NB] = s[1023];
}

// Scatter keys into bucket regions; record each point's slot (pos, coalesced).
__global__ void k3_scatter(const unsigned* __restrict__ upt, const unsigned* __restrict__ hist,
                           const unsigned* __restrict__ boff, unsigned* __restrict__ pk,
                           unsigned* __restrict__ pos, int n, int cpb) {
  __shared__ unsigned cur[NB];
  const int c = blockIdx.x;
  for (int b = threadIdx.x; b < NB; b += blockDim.x)
    cur[b] = boff[b] + hist[(size_t)c * NB + b];
  __syncthreads();
  const int lo = c * cpb, hi = min(n, lo + cpb);
  for (int i = lo + threadIdx.x; i < hi; i += blockDim.x) {
    unsigned u = upt[i];
    if (u == 0xFFFFFFFFu) continue;
    unsigned p = atomicAdd(&cur[u >> BBITS], 1u);
    pk[p] = u;
    pos[i] = p;
  }
}

// Per-bucket: LDS bitmap + swizzled word-prefix -> dcnt, compacted distinct
// keys dk[boff[b]+j], per-pair LOCAL rank -> mapval[p] (contiguous).
__global__ void __launch_bounds__(1024) k4_rank(
    const unsigned* __restrict__ pk, const unsigned* __restrict__ boff,
    unsigned* __restrict__ dcnt, unsigned* __restrict__ dk,
    unsigned* __restrict__ mapval) {
  __shared__ unsigned bits[BWORDS];  // 32KB, rank-swizzled via sw()
  __shared__ unsigned wpre[BWORDS];  // 32KB, rank-swizzled
  __shared__ unsigned s[1024];       //  4KB
  const int tid = threadIdx.x;
  const int bid = blockIdx.x;

  for (int w = tid; w < BWORDS; w += 1024) bits[w] = 0;
  __syncthreads();
  const unsigned lo = boff[bid], hi = boff[bid + 1];
  const unsigned base = (unsigned)bid << BBITS;
  for (unsigned p = lo + tid; p < hi; p += 1024) {
    unsigned local = pk[p] - base;
    atomicOr(&bits[sw(local >> 5)], 1u << (local & 31));
  }
  __syncthreads();

  // per-word exclusive popcount prefix; thread owns rank-words 8t..8t+7 at
  // slots {t, 1024+t, ...} -> stride-1, conflict-free.
  unsigned c8[8];
  unsigned t = 0;
  #pragma unroll
  for (int j = 0; j < 8; j++) {
    unsigned p = __popc(bits[j * 1024 + tid]);
    c8[j] = t;
    t += p;
  }
  s[tid] = t;
  __syncthreads();
  for (int o = 1; o < 1024; o <<= 1) {
    unsigned add = (tid >= o) ? s[tid - o] : 0u;
    __syncthreads();
    s[tid] += add;
    __syncthreads();
  }
  const unsigned excl = s[tid] - t;
  #pragma unroll
  for (int j = 0; j < 8; j++) wpre[j * 1024 + tid] = excl + c8[j];
  if (tid == 1023) dcnt[bid] = s[1023];
  __syncthreads();

  // enumerate set bits in rank order -> compacted distinct keys
  const unsigned dkb = lo;  // dk shares boff layout (dcnt[b] <= npoints[b])
  #pragma unroll
  for (int j = 0; j < 8; j++) {
    const int slot = j * 1024 + tid;
    unsigned m = bits[slot];
    unsigned r = wpre[slot];
    const unsigned lbase = (unsigned)(tid * 8 + j) << 5;
    while (m) {
      int bit = __ffs(m) - 1;
      m &= m - 1;
      dk[dkb + r] = base + lbase + (unsigned)bit;
      r++;
    }
  }

  // per-pair LOCAL rank -> mapval[p] (contiguous write)
  for (unsigned p = lo + tid; p < hi; p += 1024) {
    unsigned local = pk[p] - base;
    int slot = sw((int)(local >> 5));
    mapval[p] = wpre[slot] + (unsigned)__popc(bits[slot] & ((1u << (local & 31)) - 1u));
  }
}

// Per-bucket: drank = prefix over dcnt (L2-resident); decode dk -> rows
// (coalesced); drank_tbl[b]. Pad blocks: tail rows + n_voxels.
__global__ void k6_emit(const unsigned* __restrict__ dk, const unsigned* __restrict__ boff,
                        const unsigned* __restrict__ dcnt, unsigned* __restrict__ drank_tbl,
                        float* __restrict__ out_coords, float* __restrict__ out_feats,
                        float* __restrict__ out_nvox, int n) {
  __shared__ unsigned s[256];
  const int tid = threadIdx.x;
  const int bid = blockIdx.x;

  if (bid >= NB) {
    // pad role: n_voxels = sum(dcnt); rows [nv, n) get coords=-1, feats=0
    unsigned part = 0;
    for (int k = tid; k < NB; k += 256) part += dcnt[k];
    s[tid] = part;
    __syncthreads();
    for (int o = 128; o > 0; o >>= 1) {
      if (tid < o) s[tid] += s[tid + o];
      __syncthreads();
    }
    const unsigned nv = s[0];
    if (bid == NB && tid == 0) *out_nvox = (float)nv;
    const int row = (bid - NB) * 256 + tid;
    if (row < n && (unsigned)row >= nv) {
      float* c = out_coords + (size_t)row * 4;
      c[0] = -1.0f; c[1] = -1.0f; c[2] = -1.0f; c[3] = -1.0f;
      float* f = out_feats + (size_t)row * 3;
      f[0] = 0.0f; f[1] = 0.0f; f[2] = 0.0f;
    }
    return;
  }

  // drank = sum(dcnt[0..bid))  (dcnt is 4.9KB, L2-resident)
  unsigned part = 0;
  for (int k = tid; k < bid; k += 256) part += dcnt[k];
  s[tid] = part;
  __syncthreads();
  for (int o = 128; o > 0; o >>= 1) {
    if (tid < o) s[tid] += s[tid + o];
    __syncthreads();
  }
  const unsigned drank = s[0];
  if (tid == 0) drank_tbl[bid] = drank;

  const unsigned dc = dcnt[bid];
  const unsigned dkb = boff[bid];
  for (unsigned j = tid; j < dc; j += 256) {
    unsigned u = dk[dkb + j];
    int bat = (int)(u / (unsigned)GXYZ);
    int rem = (int)(u % (unsigned)GXYZ);
    int x = rem / YZ, ry = rem % YZ;
    int y = ry / GZ, z = ry % GZ;
    const size_t r = drank + j;
    float* cc = out_coords + r * 4;
    cc[0] = (float)bat; cc[1] = (float)z; cc[2] = (float)y; cc[3] = (float)x;
    float* ff = out_feats + r * 3;
    ff[0] = -50.0f + ((float)x + 0.5f) * 0.1f;
    ff[1] = -50.0f + ((float)y + 0.5f) * 0.1f;
    ff[2] = -5.0f + ((float)z + 0.5f) * 0.1f;
  }
}

__global__ void k7_map(const unsigned* __restrict__ upt, const unsigned* __restrict__ pos,
                       const unsigned* __restrict__ mapval, const unsigned* __restrict__ drank_tbl,
                       float* __restrict__ out_map, int n) {
  int i = blockIdx.x * blockDim.x + threadIdx.x;
  if (i >= n) return;
  unsigned u = upt[i];
  if (u == 0xFFFFFFFFu) {  // pos[i] is poison for invalid points: keep the
    out_map[i] = -1.0f;    // dependent gathers provably unreachable
    return;
  }
  out_map[i] = (float)(drank_tbl[u >> BBITS] + mapval[pos[i]]);
}

}  // namespace

extern "C" void kernel_launch(void* const* d_in, const int* in_sizes, int n_in,
                              void* d_out, int out_size, void* d_ws, size_t ws_size,
                              hipStream_t stream) {
  const int N = in_sizes[0] / 3;
  const float* pts = (const float*)d_in[0];
  const int* bi = (const int*)d_in[1];
  float* out = (float*)d_out;

  unsigned* upt   = (unsigned*)d_ws;
  unsigned* pk    = (unsigned*)((char*)d_ws + OFF_PK);
  unsigned* pos   = (unsigned*)((char*)d_ws + OFF_POS);
  unsigned* mval  = (unsigned*)((char*)d_ws + OFF_MVAL);
  unsigned* dk    = (unsigned*)((char*)d_ws + OFF_DK);
  unsigned* hist  = (unsigned*)((char*)d_ws + OFF_HIST);
  unsigned* tot   = (unsigned*)((char*)d_ws + OFF_TOT);
  unsigned* boff  = (unsigned*)((char*)d_ws + OFF_BOFF);
  unsigned* dcnt  = (unsigned*)((char*)d_ws + OFF_DCNT);
  unsigned* drank = (unsigned*)((char*)d_ws + OFF_DRANK);

  float* out_coords = out;            // [N,4]
  float* out_feats  = out + 4LL * N;  // [N,3]
  float* out_map    = out + 7LL * N;  // [N]
  float* out_nvox   = out + 8LL * N;  // scalar

  const int cpb = (N + NCHUNK - 1) / NCHUNK;
  const int pad_blocks = (N + 255) / 256;

  k1_keys_hist<<<NCHUNK, 256, 0, stream>>>(pts, bi, upt, hist, N, cpb);
  k2a_chunk_pre<<<(NB * 64 + 255) / 256, 256, 0, stream>>>(hist, tot);
  k2b_scan_tot<<<1, 1024, 0, stream>>>(tot, boff);
  k3_scatter<<<NCHUNK, 256, 0, stream>>>(upt, hist, boff, pk, pos, N, cpb);
  k4_rank<<<NB, 1024, 0, stream>>>(pk, boff, dcnt, dk, mval);
  k6_emit<<<NB + pad_blocks, 256, 0, stream>>>(dk, boff, dcnt, drank,
                                               out_coords, out_feats, out_nvox, N);
  k7_map<<<(N + 255) / 256, 256, 0, stream>>>(upt, pos, mval, drank, out_map, N);
}

// Round 13
// 175.332 us; speedup vs baseline: 1.1286x; 1.0127x over previous
//
#include <hip/hip_runtime.h>

// PointVoxelizer: bucketed sorted-unique over bounded key domain.
// combined = batch*GXYZ + x*YZ + y*GZ + z in [0, 3.2e8).
// Points partitioned by key>>18 into 1221 buckets (2^18 cells = 32KB LDS
// bitmap); all random access in LDS. No global atomics.
// R9: barrier-count surgery. k4's 20-barrier 1024-thread scan -> wave shfl
// scan + 1 barrier; k6's per-block O(NB) reduce (16 barriers) -> hoisted to
// 1-block k5; k2b rewritten with wave scan. k6 is now zero-barrier streaming.
//
// Dispatches:
//   k1_keys_hist  : keys -> upt; per-(chunk,bucket) LDS histogram -> hist[c][b]
//   k2a_chunk_pre : per-bucket exclusive prefix over chunks -> tot
//   k2b_scan_tot  : 1-block wave-scan of tot -> boff[NB+1]
//   k3_scatter    : keys into bucket regions (LDS cursors); pos[i] = slot
//   k4_rank       : per-bucket LDS bitmap + swizzled word-prefix -> dcnt[b];
//                   dk[boff[b]+j]=j-th distinct key; mapval[p]=local rank
//   k5_scan_dcnt  : 1-block wave-scan of dcnt -> drank_tbl[b], n_voxels
//   k6_emit       : decode dk -> coords/feats rows (coalesced, no barriers);
//                   pad blocks fill tail rows
//   k7_map        : out_map[i] = valid ? drank_tbl[u>>18]+mapval[pos[i]] : -1

namespace {

constexpr int GX = 1000, GY = 1000, GZ = 80;
constexpr int YZ = GY * GZ;                 // 80,000
constexpr int GXYZ = GX * YZ;               // 80,000,000
constexpr int TOTAL_CELLS = GXYZ * 4;       // 320,000,000 (< 2^31)
constexpr int BBITS = 18;
constexpr int BCELLS = 1 << BBITS;          // 262,144 cells / bucket
constexpr int NB = (TOTAL_CELLS + BCELLS - 1) >> BBITS;  // 1221
constexpr int BWORDS = BCELLS / 32;         // 8192 u32 (32KB LDS bitmap)
constexpr int NCHUNK = 512;
static_assert(NCHUNK % 64 == 0, "k2a wave scan");
static_assert(NB <= 2048, "1-block scans assume <=2048 elements");

// ws layout (bytes):
//   [0,    8e6)   upt    u32[N]
//   [8e6, 16e6)   pk     u32[N]   (bucket-grouped keys)
//   [16e6,24e6)   pos    u32[N]   (point i -> slot p)
//   [24e6,32e6)   mapval u32[N]   (slot p -> local rank)
//   [32e6,40e6)   dk     u32[N]   (compacted distinct keys per bucket)
//   [40e6,42.6e6) hist   u32[NCHUNK][NB]
//   [43e6,..)     tot, boff, dcnt, drank
constexpr size_t OFF_PK    = 8000000;
constexpr size_t OFF_POS   = 16000000;
constexpr size_t OFF_MVAL  = 24000000;
constexpr size_t OFF_DK    = 32000000;
constexpr size_t OFF_HIST  = 40000000;
constexpr size_t OFF_TOT   = 43000000;
constexpr size_t OFF_BOFF  = 43100000;
constexpr size_t OFF_DCNT  = 43200000;
constexpr size_t OFF_DRANK = 43300000;

__device__ __forceinline__ int sw(int w) {  // rank-word -> LDS slot swizzle
  return ((w & 7) << 10) | (w >> 3);
}

__global__ void k1_keys_hist(const float* __restrict__ pts, const int* __restrict__ bi,
                             unsigned* __restrict__ upt, unsigned* __restrict__ hist,
                             int n, int cpb) {
  __shared__ unsigned h[NB];
  const int c = blockIdx.x;
  for (int b = threadIdx.x; b < NB; b += blockDim.x) h[b] = 0;
  __syncthreads();
  const int lo = c * cpb, hi = min(n, lo + cpb);
  for (int i = lo + threadIdx.x; i < hi; i += blockDim.x) {
    // Bit-exact mirror of reference: fp32 add/div/floor (non-contractible).
    float px = pts[3 * i + 0], py = pts[3 * i + 1], pz = pts[3 * i + 2];
    int vx = (int)floorf((px + 50.0f) / 0.1f);
    int vy = (int)floorf((py + 50.0f) / 0.1f);
    int vz = (int)floorf((pz + 5.0f) / 0.1f);
    bool valid = (vx >= 0) & (vy >= 0) & (vz >= 0) & (vx < GX) & (vy < GY) & (vz < GZ);
    unsigned u = 0xFFFFFFFFu;
    if (valid) {
      u = (unsigned)(bi[i] * GXYZ + vx * YZ + vy * GZ + vz);
      atomicAdd(&h[u >> BBITS], 1u);
    }
    upt[i] = u;
  }
  __syncthreads();
  for (int b = threadIdx.x; b < NB; b += blockDim.x)
    hist[(size_t)c * NB + b] = h[b];  // contiguous flush, no global atomics
}

// One wave per bucket: exclusive prefix of hist[*][b] across chunks (in place),
// bucket total -> tot[b].
__global__ void k2a_chunk_pre(unsigned* __restrict__ hist, unsigned* __restrict__ tot) {
  const int wid = (blockIdx.x * blockDim.x + threadIdx.x) >> 6;
  const int lane = threadIdx.x & 63;
  if (wid >= NB) return;
  unsigned run = 0;
  for (int c0 = 0; c0 < NCHUNK; c0 += 64) {
    const size_t idx = (size_t)(c0 + lane) * NB + wid;
    unsigned v = hist[idx];
    unsigned inc = v;
    for (int o = 1; o < 64; o <<= 1) {
      unsigned t = __shfl_up(inc, o);
      if (lane >= o) inc += t;
    }
    hist[idx] = run + inc - v;
    run += __shfl(inc, 63);
  }
  if (lane == 63) tot[wid] = run;
}

// 1-block exclusive scan of src[NB] via wave shfl-scan (1 barrier).
// dst gets exclusive prefixes; dst[NB] = total (boff mode); if out_total
// non-null, also writes total as float.
__device__ __forceinline__ void scan_block_2048(const unsigned* __restrict__ src,
                                                unsigned* __restrict__ dst, int nb,
                                                bool write_end, float* out_total) {
  __shared__ unsigned s16[16];
  const int tid = threadIdx.x;
  const int lane = tid & 63, wid = tid >> 6;
  unsigned v0 = (2 * tid     < nb) ? src[2 * tid]     : 0u;
  unsigned v1 = (2 * tid + 1 < nb) ? src[2 * tid + 1] : 0u;
  unsigned t = v0 + v1;
  unsigned incl = t;
  #pragma unroll
  for (int o = 1; o < 64; o <<= 1) {
    unsigned u = __shfl_up(incl, o);
    if (lane >= o) incl += u;
  }
  if (lane == 63) s16[wid] = incl;
  __syncthreads();
  unsigned woff = 0;
  for (int j = 0; j < wid; j++) woff += s16[j];
  unsigned excl = woff + incl - t;
  if (2 * tid     < nb) dst[2 * tid]     = excl;
  if (2 * tid + 1 < nb) dst[2 * tid + 1] = excl + v0;
  if (tid == 1023) {
    if (write_end) dst[nb] = excl + t;
    if (out_total) *out_total = (float)(excl + t);
  }
}

__global__ void __launch_bounds__(1024) k2b_scan_tot(const unsigned* __restrict__ tot,
                                                     unsigned* __restrict__ boff) {
  scan_block_2048(tot, boff, NB, true, nullptr);
}

__global__ void __launch_bounds__(1024) k5_scan_dcnt(const unsigned* __restrict__ dcnt,
                                                     unsigned* __restrict__ drank_tbl,
                                                     float* __restrict__ out_nvox) {
  scan_block_2048(dcnt, drank_tbl, NB, false, out_nvox);
}

// Scatter keys into bucket regions; record each point's slot (pos, coalesced).
__global__ void k3_scatter(const unsigned* __restrict__ upt, const unsigned* __restrict__ hist,
                           const unsigned* __restrict__ boff, unsigned* __restrict__ pk,
                           unsigned* __restrict__ pos, int n, int cpb) {
  __shared__ unsigned cur[NB];
  const int c = blockIdx.x;
  for (int b = threadIdx.x; b < NB; b += blockDim.x)
    cur[b] = boff[b] + hist[(size_t)c * NB + b];
  __syncthreads();
  const int lo = c * cpb, hi = min(n, lo + cpb);
  for (int i = lo + threadIdx.x; i < hi; i += blockDim.x) {
    unsigned u = upt[i];
    if (u == 0xFFFFFFFFu) continue;
    unsigned p = atomicAdd(&cur[u >> BBITS], 1u);
    pk[p] = u;
    pos[i] = p;
  }
}

// Per-bucket: LDS bitmap + swizzled word-prefix (wave-scan, 1 barrier for the
// scan) -> dcnt, compacted distinct keys dk, per-pair LOCAL rank -> mapval.
__global__ void __launch_bounds__(1024) k4_rank(
    const unsigned* __restrict__ pk, const unsigned* __restrict__ boff,
    unsigned* __restrict__ dcnt, unsigned* __restrict__ dk,
    unsigned* __restrict__ mapval) {
  __shared__ unsigned bits[BWORDS];  // 32KB, rank-swizzled via sw()
  __shared__ unsigned wpre[BWORDS];  // 32KB, rank-swizzled
  __shared__ unsigned s16[16];
  const int tid = threadIdx.x;
  const int bid = blockIdx.x;
  const int lane = tid & 63, wid = tid >> 6;

  for (int w = tid; w < BWORDS; w += 1024) bits[w] = 0;
  __syncthreads();
  const unsigned lo = boff[bid], hi = boff[bid + 1];
  const unsigned base = (unsigned)bid << BBITS;
  for (unsigned p = lo + tid; p < hi; p += 1024) {
    unsigned local = pk[p] - base;
    atomicOr(&bits[sw(local >> 5)], 1u << (local & 31));
  }
  __syncthreads();

  // thread-local popcount prefix over rank-words 8t..8t+7 (slots {t,1024+t,..}
  // -> stride-1, conflict-free), then wave shfl-scan + 1-barrier cross-wave.
  unsigned c8[8];
  unsigned t = 0;
  #pragma unroll
  for (int j = 0; j < 8; j++) {
    unsigned p = __popc(bits[j * 1024 + tid]);
    c8[j] = t;
    t += p;
  }
  unsigned incl = t;
  #pragma unroll
  for (int o = 1; o < 64; o <<= 1) {
    unsigned u = __shfl_up(incl, o);
    if (lane >= o) incl += u;
  }
  if (lane == 63) s16[wid] = incl;
  __syncthreads();
  unsigned woff = 0;
  for (int j = 0; j < wid; j++) woff += s16[j];
  const unsigned excl = woff + incl - t;
  #pragma unroll
  for (int j = 0; j < 8; j++) wpre[j * 1024 + tid] = excl + c8[j];
  if (tid == 1023) dcnt[bid] = excl + t;

  // enumerate set bits in rank order -> compacted distinct keys.
  // Uses register prefix (excl+c8) only -> no barrier needed before this.
  const unsigned dkb = lo;  // dk shares boff layout (dcnt[b] <= npoints[b])
  #pragma unroll
  for (int j = 0; j < 8; j++) {
    unsigned m = bits[j * 1024 + tid];
    unsigned r = excl + c8[j];
    const unsigned lbase = (unsigned)(tid * 8 + j) << 5;
    while (m) {
      int bit = __ffs(m) - 1;
      m &= m - 1;
      dk[dkb + r] = base + lbase + (unsigned)bit;
      r++;
    }
  }
  __syncthreads();  // wpre fully written before random reads below

  // per-pair LOCAL rank -> mapval[p] (contiguous write)
  for (unsigned p = lo + tid; p < hi; p += 1024) {
    unsigned local = pk[p] - base;
    int slot = sw((int)(local >> 5));
    mapval[p] = wpre[slot] + (unsigned)__popc(bits[slot] & ((1u << (local & 31)) - 1u));
  }
}

// Pure streaming decode, zero barriers. Pad blocks fill tail rows.
__global__ void k6_emit(const unsigned* __restrict__ dk, const unsigned* __restrict__ boff,
                        const unsigned* __restrict__ dcnt, const unsigned* __restrict__ drank_tbl,
                        const float* __restrict__ nvox_f,
                        float* __restrict__ out_coords, float* __restrict__ out_feats, int n) {
  const int tid = threadIdx.x;
  const int bid = blockIdx.x;

  if (bid >= NB) {
    const unsigned nv = (unsigned)*nvox_f;
    const int row = (bid - NB) * 256 + tid;
    if (row < n && (unsigned)row >= nv) {
      float* c = out_coords + (size_t)row * 4;
      c[0] = -1.0f; c[1] = -1.0f; c[2] = -1.0f; c[3] = -1.0f;
      float* f = out_feats + (size_t)row * 3;
      f[0] = 0.0f; f[1] = 0.0f; f[2] = 0.0f;
    }
    return;
  }

  const unsigned drank = drank_tbl[bid];
  const unsigned dc = dcnt[bid];
  const unsigned dkb = boff[bid];
  for (unsigned j = tid; j < dc; j += 256) {
    unsigned u = dk[dkb + j];
    int bat = (int)(u / (unsigned)GXYZ);
    int rem = (int)(u % (unsigned)GXYZ);
    int x = rem / YZ, ry = rem % YZ;
    int y = ry / GZ, z = ry % GZ;
    const size_t r = drank + j;
    float* cc = out_coords + r * 4;
    cc[0] = (float)bat; cc[1] = (float)z; cc[2] = (float)y; cc[3] = (float)x;
    float* ff = out_feats + r * 3;
    ff[0] = -50.0f + ((float)x + 0.5f) * 0.1f;
    ff[1] = -50.0f + ((float)y + 0.5f) * 0.1f;
    ff[2] = -5.0f + ((float)z + 0.5f) * 0.1f;
  }
}

__global__ void k7_map(const unsigned* __restrict__ upt, const unsigned* __restrict__ pos,
                       const unsigned* __restrict__ mapval, const unsigned* __restrict__ drank_tbl,
                       float* __restrict__ out_map, int n) {
  int i = blockIdx.x * blockDim.x + threadIdx.x;
  if (i >= n) return;
  unsigned u = upt[i];
  if (u == 0xFFFFFFFFu) {  // pos[i] is poison for invalid points: keep the
    out_map[i] = -1.0f;    // dependent gathers provably unreachable
    return;
  }
  out_map[i] = (float)(drank_tbl[u >> BBITS] + mapval[pos[i]]);
}

}  // namespace

extern "C" void kernel_launch(void* const* d_in, const int* in_sizes, int n_in,
                              void* d_out, int out_size, void* d_ws, size_t ws_size,
                              hipStream_t stream) {
  const int N = in_sizes[0] / 3;
  const float* pts = (const float*)d_in[0];
  const int* bi = (const int*)d_in[1];
  float* out = (float*)d_out;

  unsigned* upt   = (unsigned*)d_ws;
  unsigned* pk    = (unsigned*)((char*)d_ws + OFF_PK);
  unsigned* pos   = (unsigned*)((char*)d_ws + OFF_POS);
  unsigned* mval  = (unsigned*)((char*)d_ws + OFF_MVAL);
  unsigned* dk    = (unsigned*)((char*)d_ws + OFF_DK);
  unsigned* hist  = (unsigned*)((char*)d_ws + OFF_HIST);
  unsigned* tot   = (unsigned*)((char*)d_ws + OFF_TOT);
  unsigned* boff  = (unsigned*)((char*)d_ws + OFF_BOFF);
  unsigned* dcnt  = (unsigned*)((char*)d_ws + OFF_DCNT);
  unsigned* drank = (unsigned*)((char*)d_ws + OFF_DRANK);

  float* out_coords = out;            // [N,4]
  float* out_feats  = out + 4LL * N;  // [N,3]
  float* out_map    = out + 7LL * N;  // [N]
  float* out_nvox   = out + 8LL * N;  // scalar

  const int cpb = (N + NCHUNK - 1) / NCHUNK;
  const int pad_blocks = (N + 255) / 256;

  k1_keys_hist<<<NCHUNK, 256, 0, stream>>>(pts, bi, upt, hist, N, cpb);
  k2a_chunk_pre<<<(NB * 64 + 255) / 256, 256, 0, stream>>>(hist, tot);
  k2b_scan_tot<<<1, 1024, 0, stream>>>(tot, boff);
  k3_scatter<<<NCHUNK, 256, 0, stream>>>(upt, hist, boff, pk, pos, N, cpb);
  k4_rank<<<NB, 1024, 0, stream>>>(pk, boff, dcnt, dk, mval);
  k5_scan_dcnt<<<1, 1024, 0, stream>>>(dcnt, drank, out_nvox);
  k6_emit<<<NB + pad_blocks, 256, 0, stream>>>(dk, boff, dcnt, drank, out_nvox,
                                               out_coords, out_feats, N);
  k7_map<<<(N + 255) / 256, 256, 0, stream>>>(upt, pos, mval, drank, out_map, N);
}